// Round 1
// baseline (894.052 us; speedup 1.0000x reference)
//
#include <hip/hip_runtime.h>
#include <hip/hip_bf16.h>

typedef __bf16 bf16;
typedef __bf16 bf16x8 __attribute__((ext_vector_type(8)));
typedef float  f32x4  __attribute__((ext_vector_type(4)));

#define F_IN  128
#define C_MID 64
#define BN_EPSF 1e-5f

// ws layout (floats):
//  [0..63]    sum G   (per channel, bias included)
//  [64..127]  sum G^2
//  [128..191] sum X
//  [192..255] sum X^2
//  [256]      sum s
//  [257]      sum s^2
//  [512 ...]  s array, N floats
//
// PHASE 0: compute G,X via bf16 MFMA, accumulate channel stats.
// PHASE 1: recompute G,X, fold BN (params derived per-block from stats),
//          s = relu(z)@Wpsi + bpsi, store s, accumulate s stats.
// Assumes N % 16 == 0 (N = 1e6 here).
template<int PHASE>
__global__ void k_main(const float* __restrict__ gate,
                       const float* __restrict__ skip,
                       const float* __restrict__ Wg,  const float* __restrict__ bg,
                       const float* __restrict__ gamma_g, const float* __restrict__ beta_g,
                       const float* __restrict__ Wx,  const float* __restrict__ bx,
                       const float* __restrict__ gamma_x, const float* __restrict__ beta_x,
                       const float* __restrict__ Wpsi, const float* __restrict__ bpsi,
                       float* __restrict__ stats, float* __restrict__ sArr, int N)
{
  __shared__ bf16x8 wfrag[2][4][4][64];   // [mat][cb][kc][lane] 32 KiB
  __shared__ float  red[256];             // phase 0 block stat reduce
  __shared__ float  parm[3*64];           // phase 1: Ag, Ax, Ktot
  __shared__ float  sredS[2];             // phase 1 block s-stat reduce

  const int tid = threadIdx.x;

  // ---- stage weight fragments into LDS (fragment-ordered, bf16) ----
  for (int e = tid; e < 2048; e += 256) {
    const int mat = e >> 10;
    const int cb  = (e >> 8) & 3;
    const int kc  = (e >> 6) & 3;
    const int ln  = e & 63;
    const int c   = cb*16 + (ln & 15);
    const int k0  = kc*32 + (ln >> 4)*8;
    const float* W = mat ? Wx : Wg;
    bf16x8 t;
#pragma unroll
    for (int j = 0; j < 8; ++j) t[j] = (bf16)W[(k0 + j)*C_MID + c];
    wfrag[mat][cb][kc][ln] = t;
  }
  if (PHASE == 0) {
    red[tid] = 0.f;
  } else {
    if (tid < C_MID) {
      const float inv_n = 1.0f / (float)N;
      const float mG = stats[tid]       * inv_n;
      const float vG = stats[64  + tid] * inv_n - mG*mG;
      const float mX = stats[128 + tid] * inv_n;
      const float vX = stats[192 + tid] * inv_n - mX*mX;
      const float Ag = gamma_g[tid] * rsqrtf(vG + BN_EPSF);
      const float Ax = gamma_x[tid] * rsqrtf(vX + BN_EPSF);
      parm[tid]        = Ag;
      parm[64  + tid]  = Ax;
      parm[128 + tid]  = (bg[tid] - mG)*Ag + beta_g[tid] + (bx[tid] - mX)*Ax + beta_x[tid];
    }
    if (tid < 2) sredS[tid] = 0.f;
  }
  __syncthreads();

  const int lane  = tid & 63;
  const int wid   = tid >> 6;
  const int row16 = lane & 15;   // A row select / D col (channel)
  const int quad  = lane >> 4;   // 0..3

  const int ngroups = N >> 4;
  const int gwave   = blockIdx.x*4 + wid;
  const int nwaves  = gridDim.x*4;

  float bgv[4], bxv[4], pAg[4], pAx[4], pKt[4], pwv[4];
#pragma unroll
  for (int cb = 0; cb < 4; ++cb) {
    const int c = cb*16 + row16;
    if (PHASE == 0) { bgv[cb] = bg[c]; bxv[cb] = bx[c]; }
    else { pAg[cb] = parm[c]; pAx[cb] = parm[64+c]; pKt[cb] = parm[128+c]; pwv[cb] = Wpsi[c]; }
  }
  const float bpsi0 = (PHASE == 1) ? bpsi[0] : 0.f;

  float sG[4]  = {0,0,0,0}, sG2[4] = {0,0,0,0};
  float sX[4]  = {0,0,0,0}, sX2[4] = {0,0,0,0};
  float aS = 0.f, aS2 = 0.f;

  for (int g = gwave; g < ngroups; g += nwaves) {
    const size_t rowoff = (size_t)(g*16 + row16) * F_IN + quad*8;
    const float* pg = gate + rowoff;
    const float* px = skip + rowoff;
    bf16x8 ag[4], ax[4];
#pragma unroll
    for (int kc = 0; kc < 4; ++kc) {
      f32x4 g0 = *(const f32x4*)(pg + kc*32);
      f32x4 g1 = *(const f32x4*)(pg + kc*32 + 4);
      f32x4 x0 = *(const f32x4*)(px + kc*32);
      f32x4 x1 = *(const f32x4*)(px + kc*32 + 4);
      bf16x8 tg, tx;
#pragma unroll
      for (int j = 0; j < 4; ++j) {
        tg[j] = (bf16)g0[j]; tg[4+j] = (bf16)g1[j];
        tx[j] = (bf16)x0[j]; tx[4+j] = (bf16)x1[j];
      }
      ag[kc] = tg; ax[kc] = tx;
    }
    f32x4 accG[4], accX[4];
#pragma unroll
    for (int cb = 0; cb < 4; ++cb) {
      accG[cb] = f32x4{0.f,0.f,0.f,0.f};
      accX[cb] = f32x4{0.f,0.f,0.f,0.f};
    }
#pragma unroll
    for (int cb = 0; cb < 4; ++cb) {
#pragma unroll
      for (int kc = 0; kc < 4; ++kc) {
        accG[cb] = __builtin_amdgcn_mfma_f32_16x16x32_bf16(ag[kc], wfrag[0][cb][kc][lane], accG[cb], 0, 0, 0);
        accX[cb] = __builtin_amdgcn_mfma_f32_16x16x32_bf16(ax[kc], wfrag[1][cb][kc][lane], accX[cb], 0, 0, 0);
      }
    }
    if (PHASE == 0) {
#pragma unroll
      for (int cb = 0; cb < 4; ++cb) {
#pragma unroll
        for (int j = 0; j < 4; ++j) {
          const float vg = accG[cb][j] + bgv[cb];
          const float vx = accX[cb][j] + bxv[cb];
          sG[cb] += vg; sG2[cb] += vg*vg;
          sX[cb] += vx; sX2[cb] += vx*vx;
        }
      }
    } else {
      float ps[4] = {0,0,0,0};
#pragma unroll
      for (int cb = 0; cb < 4; ++cb) {
#pragma unroll
        for (int j = 0; j < 4; ++j) {
          float z = accG[cb][j]*pAg[cb] + accX[cb][j]*pAx[cb] + pKt[cb];
          z = fmaxf(z, 0.f);
          ps[j] += z * pwv[cb];
        }
      }
#pragma unroll
      for (int j = 0; j < 4; ++j) {
        ps[j] += __shfl_xor(ps[j], 1, 64);
        ps[j] += __shfl_xor(ps[j], 2, 64);
        ps[j] += __shfl_xor(ps[j], 4, 64);
        ps[j] += __shfl_xor(ps[j], 8, 64);
      }
      if (row16 == 0) {
#pragma unroll
        for (int j = 0; j < 4; ++j) {
          const float sv = ps[j] + bpsi0;
          sArr[g*16 + quad*4 + j] = sv;
          aS += sv; aS2 += sv*sv;
        }
      }
    }
  }

  if (PHASE == 0) {
#pragma unroll
    for (int cb = 0; cb < 4; ++cb) {
      sG[cb]  += __shfl_xor(sG[cb], 16, 64);  sG[cb]  += __shfl_xor(sG[cb], 32, 64);
      sG2[cb] += __shfl_xor(sG2[cb],16, 64);  sG2[cb] += __shfl_xor(sG2[cb],32, 64);
      sX[cb]  += __shfl_xor(sX[cb], 16, 64);  sX[cb]  += __shfl_xor(sX[cb], 32, 64);
      sX2[cb] += __shfl_xor(sX2[cb],16, 64);  sX2[cb] += __shfl_xor(sX2[cb],32, 64);
    }
    if (lane < 16) {
#pragma unroll
      for (int cb = 0; cb < 4; ++cb) {
        const int c = cb*16 + lane;
        atomicAdd(&red[c],        sG[cb]);
        atomicAdd(&red[64  + c],  sG2[cb]);
        atomicAdd(&red[128 + c],  sX[cb]);
        atomicAdd(&red[192 + c],  sX2[cb]);
      }
    }
    __syncthreads();
    atomicAdd(&stats[tid], red[tid]);
  } else {
    aS  += __shfl_xor(aS, 16, 64);  aS  += __shfl_xor(aS, 32, 64);
    aS2 += __shfl_xor(aS2,16, 64);  aS2 += __shfl_xor(aS2,32, 64);
    if (lane == 0) { atomicAdd(&sredS[0], aS); atomicAdd(&sredS[1], aS2); }
    __syncthreads();
    if (tid == 0) { atomicAdd(&stats[256], sredS[0]); atomicAdd(&stats[257], sredS[1]); }
  }
}

__global__ void k_out(const float* __restrict__ skip,
                      const float* __restrict__ sArr,
                      const float* __restrict__ stats,
                      const float* __restrict__ gamma_psi,
                      const float* __restrict__ beta_psi,
                      float* __restrict__ out, int N)
{
  const float inv_n = 1.0f / (float)N;
  const float m = stats[256] * inv_n;
  const float v = stats[257] * inv_n - m*m;
  const float A = gamma_psi[0] * rsqrtf(v + BN_EPSF);
  const float B = beta_psi[0] - m*A;
  const long total  = (long)N * (F_IN/4);
  const long stride = (long)gridDim.x * blockDim.x;
  for (long i = (long)blockIdx.x*blockDim.x + threadIdx.x; i < total; i += stride) {
    const int p = (int)(i >> 5);        // 32 float4 per point
    const float t = sArr[p]*A + B;
    const float psi = 1.0f / (1.0f + __expf(-t));
    f32x4 vv = ((const f32x4*)skip)[i];
    ((f32x4*)out)[i] = vv * psi;
  }
}

extern "C" void kernel_launch(void* const* d_in, const int* in_sizes, int n_in,
                              void* d_out, int out_size, void* d_ws, size_t ws_size,
                              hipStream_t stream)
{
  const float* gate      = (const float*)d_in[0];
  const float* skip      = (const float*)d_in[1];
  const float* Wg        = (const float*)d_in[2];
  const float* bg        = (const float*)d_in[3];
  const float* gamma_g   = (const float*)d_in[4];
  const float* beta_g    = (const float*)d_in[5];
  const float* Wx        = (const float*)d_in[6];
  const float* bx        = (const float*)d_in[7];
  const float* gamma_x   = (const float*)d_in[8];
  const float* beta_x    = (const float*)d_in[9];
  const float* Wpsi      = (const float*)d_in[10];
  const float* bpsi      = (const float*)d_in[11];
  const float* gamma_psi = (const float*)d_in[12];
  const float* beta_psi  = (const float*)d_in[13];

  float* ws  = (float*)d_ws;
  float* out = (float*)d_out;
  const int N = in_sizes[0] / F_IN;

  // zero the stats accumulators (ws is NOT re-poisoned between replays)
  hipMemsetAsync(d_ws, 0, 512*sizeof(float), stream);

  dim3 blk(256);
  k_main<0><<<dim3(1024), blk, 0, stream>>>(gate, skip, Wg, bg, gamma_g, beta_g,
                                            Wx, bx, gamma_x, beta_x, Wpsi, bpsi,
                                            ws, ws + 512, N);
  k_main<1><<<dim3(1024), blk, 0, stream>>>(gate, skip, Wg, bg, gamma_g, beta_g,
                                            Wx, bx, gamma_x, beta_x, Wpsi, bpsi,
                                            ws, ws + 512, N);
  k_out<<<dim3(2048), blk, 0, stream>>>(skip, ws + 512, ws, gamma_psi, beta_psi, out, N);
}

// Round 2
// 613.906 us; speedup vs baseline: 1.4563x; 1.4563x over previous
//
#include <hip/hip_runtime.h>
#include <hip/hip_bf16.h>

typedef __bf16 bf16;
typedef __bf16 bf16x4 __attribute__((ext_vector_type(4)));
typedef __bf16 bf16x8 __attribute__((ext_vector_type(8)));
typedef float  f32x4  __attribute__((ext_vector_type(4)));

#define F_IN  128
#define C_MID 64
#define BN_EPSF 1e-5f

// ws layout (floats):
//  [0..63]   sum rawG   [64..127]  sum rawG^2
//  [128..191] sum rawX  [192..255] sum rawX^2
//  [256],[257] sum s, sum s^2
//  [512...]  s array (N floats)
// gx scratch = d_out (256 MB of bf16, dead before final pass):
//  per group g (16 points): G block 2048 B at g*4096, X block at g*4096+2048.
//  Within a block: lane*32 B = [cb0 j0..3][cb1][cb2][cb3] bf16,
//  value = point (g*16 + quad*4 + j), channel (cb*16 + row16).

// PHASE 0: contiguous-load gate/skip, per-wave LDS redistribute (XOR swizzle),
// MFMA vs LDS-staged weights, accumulate raw stats, store G,X bf16.
__global__ __launch_bounds__(256, 4) void k_p0(
    const float* __restrict__ gate, const float* __restrict__ skip,
    const float* __restrict__ Wg,   const float* __restrict__ Wx,
    float* __restrict__ stats, bf16* __restrict__ gx, int ngroups)
{
  __shared__ bf16x8 wfrag[2][4][4][64];          // 32 KiB, fragment-ordered weights
  __shared__ float  red[256];                    // block stat reduce
  __shared__ __align__(16) bf16 atile[4][2048];  // 4 KiB per-wave A tile (16x128 bf16)

  const int tid = threadIdx.x;

  // stage weights (bf16, fragment order: B-frag col=ln&15 -> channel, k=(ln>>4)*8+j)
  for (int e = tid; e < 2048; e += 256) {
    const int mat = e >> 10, cb = (e >> 8) & 3, kc = (e >> 6) & 3, ln = e & 63;
    const int c  = cb*16 + (ln & 15);
    const int k0 = kc*32 + (ln >> 4)*8;
    const float* W = mat ? Wx : Wg;
    bf16x8 t;
#pragma unroll
    for (int j = 0; j < 8; ++j) t[j] = (bf16)W[(k0 + j)*C_MID + c];
    wfrag[mat][cb][kc][ln] = t;
  }
  red[tid] = 0.f;
  __syncthreads();

  const int lane = tid & 63, wid = tid >> 6;
  const int mat  = wid & 1;                 // wave handles one matrix
  const int row16 = lane & 15, quad = lane >> 4;
  const float* src = mat ? skip : gate;

  const int stream0  = blockIdx.x*2 + (wid >> 1);
  const int nstreams = gridDim.x*2;

  bf16* at = atile[wid];
  float s1[4] = {0,0,0,0}, s2[4] = {0,0,0,0};

  for (int g = stream0; g < ngroups; g += nstreams) {
    const float* p = src + (size_t)g * 2048;
    // 8 contiguous 1-KB wave loads (lane-linear, k_out pattern)
    f32x4 L[8];
#pragma unroll
    for (int i = 0; i < 8; ++i) L[i] = *(const f32x4*)(p + i*256 + lane*4);
    // cvt -> bf16, swizzled ds_write (byte ^= (row&7)<<4)
#pragma unroll
    for (int i = 0; i < 8; ++i) {
      const int r = i*2 + (lane >> 5);
      const int cbyte = ((lane & 31)*8) ^ ((r & 7) << 4);
      bf16x4 t;
#pragma unroll
      for (int j = 0; j < 4; ++j) t[j] = (bf16)L[i][j];
      *(bf16x4*)((char*)at + r*256 + cbyte) = t;
    }
    // fragment reads (same swizzle)
    bf16x8 af[4];
#pragma unroll
    for (int kc = 0; kc < 4; ++kc) {
      const int cbyte = (kc*64 + quad*16) ^ ((row16 & 7) << 4);
      af[kc] = *(const bf16x8*)((const char*)at + row16*256 + cbyte);
    }
    f32x4 acc[4];
#pragma unroll
    for (int cb = 0; cb < 4; ++cb) acc[cb] = f32x4{0.f,0.f,0.f,0.f};
#pragma unroll
    for (int cb = 0; cb < 4; ++cb)
#pragma unroll
      for (int kc = 0; kc < 4; ++kc)
        acc[cb] = __builtin_amdgcn_mfma_f32_16x16x32_bf16(af[kc], wfrag[mat][cb][kc][lane], acc[cb], 0, 0, 0);

    // stats on raw values + pack + contiguous bf16 store
    bf16x8 o0, o1;
#pragma unroll
    for (int cb = 0; cb < 4; ++cb) {
#pragma unroll
      for (int j = 0; j < 4; ++j) {
        const float v = acc[cb][j];
        s1[cb] += v; s2[cb] += v*v;
        if (cb < 2) o0[cb*4 + j] = (bf16)v; else o1[(cb-2)*4 + j] = (bf16)v;
      }
    }
    char* dst = (char*)gx + ((size_t)g*2 + mat)*2048 + lane*32;
    *(bf16x8*)dst        = o0;
    *(bf16x8*)(dst + 16) = o1;
  }

  // reduce over quads (xor 16,32), then per-channel block/global reduce
#pragma unroll
  for (int cb = 0; cb < 4; ++cb) {
    s1[cb] += __shfl_xor(s1[cb], 16, 64);  s1[cb] += __shfl_xor(s1[cb], 32, 64);
    s2[cb] += __shfl_xor(s2[cb], 16, 64);  s2[cb] += __shfl_xor(s2[cb], 32, 64);
  }
  if (lane < 16) {
#pragma unroll
    for (int cb = 0; cb < 4; ++cb) {
      const int c = cb*16 + lane;
      atomicAdd(&red[mat*128 + c],      s1[cb]);
      atomicAdd(&red[mat*128 + 64 + c], s2[cb]);
    }
  }
  __syncthreads();
  atomicAdd(&stats[tid], red[tid]);
}

// PHASE 1: read G,X bf16, fold BN (biases cancel in BN), s = relu(z)@Wpsi,
// store s (fp32) + s stats.
__global__ __launch_bounds__(256) void k_p1(
    const bf16* __restrict__ gx, const float* __restrict__ stats,
    const float* __restrict__ gamma_g, const float* __restrict__ beta_g,
    const float* __restrict__ gamma_x, const float* __restrict__ beta_x,
    const float* __restrict__ Wpsi,
    float* __restrict__ sArr, float* __restrict__ sstat,
    int ngroups, float inv_n)
{
  __shared__ float pAg[64], pAx[64], pK[64], pW[64];
  const int tid = threadIdx.x;
  if (tid < 64) {
    const float mG = stats[tid]*inv_n,       vG = stats[64 + tid]*inv_n  - mG*mG;
    const float mX = stats[128 + tid]*inv_n, vX = stats[192 + tid]*inv_n - mX*mX;
    const float Ag = gamma_g[tid] * rsqrtf(vG + BN_EPSF);
    const float Ax = gamma_x[tid] * rsqrtf(vX + BN_EPSF);
    pAg[tid] = Ag; pAx[tid] = Ax;
    pK[tid]  = beta_g[tid] - mG*Ag + beta_x[tid] - mX*Ax;
    pW[tid]  = Wpsi[tid];
  }
  __syncthreads();

  const int lane = tid & 63, wid = tid >> 6;
  const int row16 = lane & 15, quad = lane >> 4;
  float Ag[4], Ax[4], K[4], W[4];
#pragma unroll
  for (int cb = 0; cb < 4; ++cb) {
    const int c = cb*16 + row16;
    Ag[cb] = pAg[c]; Ax[cb] = pAx[c]; K[cb] = pK[c]; W[cb] = pW[c];
  }

  float aS = 0.f, aS2 = 0.f;
  const int g0 = blockIdx.x*4 + wid, ng = gridDim.x*4;
  for (int g = g0; g < ngroups; g += ng) {
    const char* base = (const char*)gx + (size_t)g*4096 + lane*32;
    const bf16x8 gA = *(const bf16x8*)(base);
    const bf16x8 gB = *(const bf16x8*)(base + 16);
    const bf16x8 xA = *(const bf16x8*)(base + 2048);
    const bf16x8 xB = *(const bf16x8*)(base + 2048 + 16);
    float ps[4] = {0,0,0,0};
#pragma unroll
    for (int cb = 0; cb < 4; ++cb) {
#pragma unroll
      for (int j = 0; j < 4; ++j) {
        const float gv = (float)(cb < 2 ? gA[cb*4 + j] : gB[(cb-2)*4 + j]);
        const float xv = (float)(cb < 2 ? xA[cb*4 + j] : xB[(cb-2)*4 + j]);
        float z = fmaf(gv, Ag[cb], fmaf(xv, Ax[cb], K[cb]));
        z = fmaxf(z, 0.f);
        ps[j] = fmaf(z, W[cb], ps[j]);
      }
    }
#pragma unroll
    for (int j = 0; j < 4; ++j) {
      ps[j] += __shfl_xor(ps[j], 1, 64);
      ps[j] += __shfl_xor(ps[j], 2, 64);
      ps[j] += __shfl_xor(ps[j], 4, 64);
      ps[j] += __shfl_xor(ps[j], 8, 64);
    }
    if (row16 == 0) {
#pragma unroll
      for (int j = 0; j < 4; ++j) {
        const float sv = ps[j];
        sArr[g*16 + quad*4 + j] = sv;
        aS += sv; aS2 += sv*sv;
      }
    }
  }
  aS  += __shfl_xor(aS, 16, 64);  aS  += __shfl_xor(aS, 32, 64);
  aS2 += __shfl_xor(aS2,16, 64);  aS2 += __shfl_xor(aS2,32, 64);
  if (lane == 0) { atomicAdd(&sstat[0], aS); atomicAdd(&sstat[1], aS2); }
}

// PHASE 2: out = skip * sigmoid(BN(s))  (bpsi cancels in BN)
__global__ void k_out(const float* __restrict__ skip,
                      const float* __restrict__ sArr,
                      const float* __restrict__ sstat,
                      const float* __restrict__ gamma_psi,
                      const float* __restrict__ beta_psi,
                      float* __restrict__ out, int N)
{
  const float inv_n = 1.0f / (float)N;
  const float m = sstat[0] * inv_n;
  const float v = sstat[1] * inv_n - m*m;
  const float A = gamma_psi[0] * rsqrtf(v + BN_EPSF);
  const float B = beta_psi[0] - m*A;
  const long total  = (long)N * (F_IN/4);
  const long stride = (long)gridDim.x * blockDim.x;
  for (long i = (long)blockIdx.x*blockDim.x + threadIdx.x; i < total; i += stride) {
    const int p = (int)(i >> 5);        // 32 f32x4 per point
    const float t = sArr[p]*A + B;
    const float psi = 1.0f / (1.0f + __expf(-t));
    f32x4 vv = ((const f32x4*)skip)[i];
    ((f32x4*)out)[i] = vv * psi;
  }
}

extern "C" void kernel_launch(void* const* d_in, const int* in_sizes, int n_in,
                              void* d_out, int out_size, void* d_ws, size_t ws_size,
                              hipStream_t stream)
{
  const float* gate      = (const float*)d_in[0];
  const float* skip      = (const float*)d_in[1];
  const float* Wg        = (const float*)d_in[2];
  const float* gamma_g   = (const float*)d_in[4];
  const float* beta_g    = (const float*)d_in[5];
  const float* Wx        = (const float*)d_in[6];
  const float* gamma_x   = (const float*)d_in[8];
  const float* beta_x    = (const float*)d_in[9];
  const float* Wpsi      = (const float*)d_in[10];
  const float* gamma_psi = (const float*)d_in[12];
  const float* beta_psi  = (const float*)d_in[13];

  float* ws   = (float*)d_ws;
  float* sArr = ws + 512;
  bf16*  gx   = (bf16*)d_out;      // d_out (512 MB) doubles as 256 MB scratch
  float* out  = (float*)d_out;

  const int N = in_sizes[0] / F_IN;
  const int ngroups = N / 16;

  hipMemsetAsync(d_ws, 0, 512*sizeof(float), stream);

  k_p0<<<dim3(1024), dim3(256), 0, stream>>>(gate, skip, Wg, Wx, ws, gx, ngroups);
  k_p1<<<dim3(1024), dim3(256), 0, stream>>>(gx, ws, gamma_g, beta_g, gamma_x, beta_x,
                                             Wpsi, sArr, ws + 256, ngroups, 1.0f/(float)N);
  k_out<<<dim3(2048), dim3(256), 0, stream>>>(skip, sArr, ws + 256, gamma_psi, beta_psi, out, N);
}